// Round 1
// baseline (1578.981 us; speedup 1.0000x reference)
//
#include <hip/hip_runtime.h>
#include <cstdint>
#include <cfloat>

// ---------------------------------------------------------------------------
// Generic 64x64 LDS-tiled fp32 GEMM.
//   C[m,n] = sum_k A[m,k] * B[k,n]   (+ epilogue)
// AT: A stored [K,M] (read A[k*M+m]); BT: B stored [N,K] (read B[n*K+k]).
// EPI: 0 = +bias[n]; 1 = raw; 2 = gamma*(v+bias[n]) + resid[m*N+n]
// Requires M%64==0, N%64==0, K%16==0 (true for all calls here).
// ---------------------------------------------------------------------------
#define TILE 64
#define BKK 16

template<bool AT, bool BT, int EPI>
__global__ __launch_bounds__(256) void gemm_kernel(
    const float* __restrict__ A, const float* __restrict__ B,
    const float* __restrict__ bias, float* __restrict__ C,
    int M, int N, int K,
    const float* __restrict__ gamma, const float* __restrict__ resid)
{
    __shared__ float As[BKK][TILE + 1];
    __shared__ float Bs[BKK][TILE + 1];

    const int tid = threadIdx.y * 16 + threadIdx.x;
    const int m0 = blockIdx.y * TILE;
    const int n0 = blockIdx.x * TILE;

    float acc[4][4] = {};

    for (int k0 = 0; k0 < K; k0 += BKK) {
        // --- load A tile (64x16) ---
        #pragma unroll
        for (int i = 0; i < (TILE * BKK) / 256; i++) {
            int idx = tid + i * 256;
            if (!AT) {
                int r = idx / BKK, c = idx % BKK;
                As[c][r] = A[(size_t)(m0 + r) * K + k0 + c];
            } else {
                int c = idx / TILE, r = idx % TILE;
                As[c][r] = A[(size_t)(k0 + c) * M + m0 + r];
            }
        }
        // --- load B tile (16x64) ---
        #pragma unroll
        for (int i = 0; i < (TILE * BKK) / 256; i++) {
            int idx = tid + i * 256;
            if (!BT) {
                int c = idx / TILE, r = idx % TILE;
                Bs[c][r] = B[(size_t)(k0 + c) * N + n0 + r];
            } else {
                int r = idx / BKK, c = idx % BKK;
                Bs[c][r] = B[(size_t)(n0 + r) * K + k0 + c];
            }
        }
        __syncthreads();

        #pragma unroll
        for (int k = 0; k < BKK; k++) {
            float a[4], b[4];
            #pragma unroll
            for (int r = 0; r < 4; r++) a[r] = As[k][threadIdx.y * 4 + r];
            #pragma unroll
            for (int c = 0; c < 4; c++) b[c] = Bs[k][threadIdx.x * 4 + c];
            #pragma unroll
            for (int r = 0; r < 4; r++)
                #pragma unroll
                for (int c = 0; c < 4; c++)
                    acc[r][c] = fmaf(a[r], b[c], acc[r][c]);
        }
        __syncthreads();
    }

    const float gam = (EPI == 2) ? gamma[0] : 0.f;
    #pragma unroll
    for (int r = 0; r < 4; r++) {
        int m = m0 + threadIdx.y * 4 + r;
        #pragma unroll
        for (int c = 0; c < 4; c++) {
            int n = n0 + threadIdx.x * 4 + c;
            float v = acc[r][c];
            if (EPI == 0) v += bias[n];
            else if (EPI == 2) v = gam * (v + bias[n]) + resid[(size_t)m * N + n];
            C[(size_t)m * N + n] = v;
        }
    }
}

// ---------------------------------------------------------------------------
// 2x2 max pool, stride 2. in: [B,H,W,Cc] -> out: [B,H/2,W/2,Cc]
// ---------------------------------------------------------------------------
__global__ __launch_bounds__(256) void maxpool2_kernel(
    const float* __restrict__ in, float* __restrict__ out,
    int Bn, int H, int W, int Cc)
{
    size_t idx = (size_t)blockIdx.x * blockDim.x + threadIdx.x;
    size_t total = (size_t)Bn * (H / 2) * (W / 2) * Cc;
    if (idx >= total) return;
    int c = idx % Cc;
    size_t r = idx / Cc;
    int pw = r % (W / 2); r /= (W / 2);
    int ph = r % (H / 2);
    int b = r / (H / 2);
    const float* base = in + (((size_t)b * H + 2 * ph) * W + 2 * pw) * Cc + c;
    float v0 = base[0];
    float v1 = base[Cc];
    float v2 = base[(size_t)W * Cc];
    float v3 = base[(size_t)W * Cc + Cc];
    out[idx] = fmaxf(fmaxf(v0, v1), fmaxf(v2, v3));
}

// ---------------------------------------------------------------------------
// Row softmax over 4096 columns; one block (256 threads) per row.
// ---------------------------------------------------------------------------
__global__ __launch_bounds__(256) void softmax_rows_kernel(float* __restrict__ s)
{
    __shared__ float red[4];
    const int NCOL = 4096, PT = 16;
    float* p = s + (size_t)blockIdx.x * NCOL;
    const int t = threadIdx.x;

    float v[PT];
    float mx = -FLT_MAX;
    #pragma unroll
    for (int i = 0; i < PT; i++) {
        v[i] = p[t + i * 256];
        mx = fmaxf(mx, v[i]);
    }
    #pragma unroll
    for (int o = 32; o > 0; o >>= 1) mx = fmaxf(mx, __shfl_xor(mx, o, 64));
    if ((t & 63) == 0) red[t >> 6] = mx;
    __syncthreads();
    mx = fmaxf(fmaxf(red[0], red[1]), fmaxf(red[2], red[3]));
    __syncthreads();

    float sum = 0.f;
    #pragma unroll
    for (int i = 0; i < PT; i++) {
        v[i] = __expf(v[i] - mx);
        sum += v[i];
    }
    #pragma unroll
    for (int o = 32; o > 0; o >>= 1) sum += __shfl_xor(sum, o, 64);
    if ((t & 63) == 0) red[t >> 6] = sum;
    __syncthreads();
    sum = red[0] + red[1] + red[2] + red[3];

    float inv = 1.f / sum;
    #pragma unroll
    for (int i = 0; i < PT; i++) p[t + i * 256] = v[i] * inv;
}

// ---------------------------------------------------------------------------
extern "C" void kernel_launch(void* const* d_in, const int* in_sizes, int n_in,
                              void* d_out, int out_size, void* d_ws, size_t ws_size,
                              hipStream_t stream)
{
    const float* x       = (const float*)d_in[0];
    const float* theta_w = (const float*)d_in[1];
    const float* theta_b = (const float*)d_in[2];
    const float* phi_w   = (const float*)d_in[3];
    const float* phi_b   = (const float*)d_in[4];
    const float* g_w     = (const float*)d_in[5];
    const float* g_b     = (const float*)d_in[6];
    const float* o3_w    = (const float*)d_in[7];
    const float* o3_b    = (const float*)d_in[8];
    const float* gamma   = (const float*)d_in[9];
    float* out = (float*)d_out;

    const int Bn = 8, H = 64, W = 64, C = 512, CFG = 64, CH = 256;
    const int HWn = H * W;          // 4096
    const int M = Bn * HWn;         // 32768
    const int HWD = (H / 2) * (W / 2); // 1024

    // workspace carve-up (floats): total ~27.8M floats = 111 MB
    float* ws    = (float*)d_ws;
    float* theta = ws;                                   // M*CFG     = 2.10M
    float* phiF  = theta + (size_t)M * CFG;              // M*CFG     = 2.10M
    float* gF    = phiF + (size_t)M * CFG;               // M*CH      = 8.39M
    float* phiP  = gF + (size_t)M * CH;                  // Bn*HWD*CFG= 0.52M
    float* gP    = phiP + (size_t)Bn * HWD * CFG;        // Bn*HWD*CH = 2.10M
    float* beta  = gP + (size_t)Bn * HWD * CH;           // HWD*HWn   = 4.19M (per-batch reuse)
    float* o     = beta + (size_t)HWD * HWn;             // M*CH      = 8.39M

    dim3 blk(16, 16);

    // 1-3: projections (full resolution)
    gemm_kernel<false, false, 0><<<dim3(CFG / 64, M / 64), blk, 0, stream>>>(
        x, theta_w, theta_b, theta, M, CFG, C, nullptr, nullptr);
    gemm_kernel<false, false, 0><<<dim3(CFG / 64, M / 64), blk, 0, stream>>>(
        x, phi_w, phi_b, phiF, M, CFG, C, nullptr, nullptr);
    gemm_kernel<false, false, 0><<<dim3(CH / 64, M / 64), blk, 0, stream>>>(
        x, g_w, g_b, gF, M, CH, C, nullptr, nullptr);

    // 4-5: maxpools
    {
        size_t tot = (size_t)Bn * HWD * CFG;
        maxpool2_kernel<<<dim3((tot + 255) / 256), dim3(256), 0, stream>>>(phiF, phiP, Bn, H, W, CFG);
        tot = (size_t)Bn * HWD * CH;
        maxpool2_kernel<<<dim3((tot + 255) / 256), dim3(256), 0, stream>>>(gF, gP, Bn, H, W, CH);
    }

    // 6: per-batch attention (s -> softmax -> o), beta buffer reused serially
    for (int b = 0; b < Bn; b++) {
        const float* phiPb  = phiP + (size_t)b * HWD * CFG;
        const float* thetab = theta + (size_t)b * HWn * CFG;
        const float* gPb    = gP + (size_t)b * HWD * CH;
        float* ob           = o + (size_t)b * HWn * CH;

        // s[i,j] = phi_p[i,:] . theta[j,:]  (NT)
        gemm_kernel<false, true, 1><<<dim3(HWn / 64, HWD / 64), blk, 0, stream>>>(
            phiPb, thetab, nullptr, beta, HWD, HWn, CFG, nullptr, nullptr);
        // softmax over j per row i
        softmax_rows_kernel<<<dim3(HWD), dim3(256), 0, stream>>>(beta);
        // o[j,c] = sum_i beta[i,j] * g_p[i,c]  (TN)
        gemm_kernel<true, false, 1><<<dim3(CH / 64, HWn / 64), blk, 0, stream>>>(
            beta, gPb, nullptr, ob, HWn, CH, HWD, nullptr, nullptr);
    }

    // 7: out = gamma*(o @ o3_w + o3_b) + x
    gemm_kernel<false, false, 2><<<dim3(C / 64, M / 64), blk, 0, stream>>>(
        o, o3_w, o3_b, out, M, C, CH, gamma, x);
}

// Round 2
// 267.441 us; speedup vs baseline: 5.9040x; 5.9040x over previous
//
#include <hip/hip_runtime.h>
#include <cstdint>

typedef short short8 __attribute__((ext_vector_type(8)));
typedef float floatx4 __attribute__((ext_vector_type(4)));

__device__ __forceinline__ unsigned short f2bf(float f) {
    unsigned int u = __builtin_bit_cast(unsigned int, f);
    u += 0x7FFFu + ((u >> 16) & 1u);
    return (unsigned short)(u >> 16);
}
__device__ __forceinline__ float bf2f(unsigned short h) {
    unsigned int u = ((unsigned int)h) << 16;
    return __builtin_bit_cast(float, u);
}

__device__ __forceinline__ void async_copy16(const void* g, void* lds) {
    __builtin_amdgcn_global_load_lds(
        (const __attribute__((address_space(1))) void*)g,
        (__attribute__((address_space(3))) void*)lds, 16, 0, 0);
}

// ---------------------------------------------------------------------------
// m97-style bf16 MFMA GEMM. C[m,n] = sum_k A[m,k]*B[n,k]  (B given as [N,K])
// Block tile 128x128, BK=32, 4 waves (2x2), each wave 64x64 via 4x4 MFMA tiles.
// EPI: 0 = bf16 raw; 1 = bf16 +bias[n]; 2 = fp32 gamma*(v+bias[n])+resid;
//      3 = bf16 exp(v-20) and atomicAdd column sums into lbuf[z*1024+n].
// ---------------------------------------------------------------------------
template<int EPI>
__global__ __launch_bounds__(256) void mfma_gemm(
    const unsigned short* __restrict__ A, const unsigned short* __restrict__ B,
    void* __restrict__ Cout, const float* __restrict__ bias,
    const float* __restrict__ gamma, const float* __restrict__ resid,
    float* __restrict__ lbuf,
    int lda, int ldb, int ldc, int K,
    long long sA, long long sB, long long sC)
{
    __shared__ unsigned short As[4096];   // [128][32]
    __shared__ unsigned short Bs[4096];   // [128][32]

    const int tid = threadIdx.x;
    const int wv = tid >> 6, ln = tid & 63;
    const int r16 = ln & 15, q8 = ln >> 4;
    const int wm = (wv >> 1) * 64, wn = (wv & 1) * 64;
    const int m0 = blockIdx.y * 128, n0 = blockIdx.x * 128;
    const int zb = blockIdx.z;

    const unsigned short* Ag = A + (long long)zb * sA;
    const unsigned short* Bg = B + (long long)zb * sB;

    floatx4 acc[4][4] = {};

    for (int k0 = 0; k0 < K; k0 += 32) {
        #pragma unroll
        for (int q = 0; q < 2; ++q) {
            int chunk = wv * 2 + q;              // 0..7
            int e = (chunk << 9) + ln * 8;       // element index into 128x32 tile
            int row = e >> 5, col = e & 31;
            async_copy16(Ag + (size_t)(m0 + row) * lda + (k0 + col), &As[chunk << 9]);
            async_copy16(Bg + (size_t)(n0 + row) * ldb + (k0 + col), &Bs[chunk << 9]);
        }
        __syncthreads();

        short8 af[4], bff[4];
        #pragma unroll
        for (int i = 0; i < 4; ++i) {
            af[i]  = *(const short8*)&As[(wm + i * 16 + r16) * 32 + q8 * 8];
            bff[i] = *(const short8*)&Bs[(wn + i * 16 + r16) * 32 + q8 * 8];
        }
        #pragma unroll
        for (int mi = 0; mi < 4; ++mi)
            #pragma unroll
            for (int ni = 0; ni < 4; ++ni)
                acc[mi][ni] = __builtin_amdgcn_mfma_f32_16x16x32_bf16(
                    af[mi], bff[ni], acc[mi][ni], 0, 0, 0);
        __syncthreads();
    }

    if (EPI == 2) {
        float* C = (float*)Cout;
        const float gm = gamma[0];
        #pragma unroll
        for (int ni = 0; ni < 4; ++ni) {
            const int n = n0 + wn + ni * 16 + r16;
            const float bs = bias[n];
            #pragma unroll
            for (int mi = 0; mi < 4; ++mi)
                #pragma unroll
                for (int r = 0; r < 4; ++r) {
                    int m = m0 + wm + mi * 16 + q8 * 4 + r;
                    C[(size_t)m * ldc + n] = gm * (acc[mi][ni][r] + bs) + resid[(size_t)m * ldc + n];
                }
        }
    } else {
        unsigned short* C = (unsigned short*)Cout + (long long)zb * sC;
        float colsum[4] = {0.f, 0.f, 0.f, 0.f};
        #pragma unroll
        for (int ni = 0; ni < 4; ++ni) {
            const int n = n0 + wn + ni * 16 + r16;
            const float bs = (EPI == 1) ? bias[n] : 0.f;
            #pragma unroll
            for (int mi = 0; mi < 4; ++mi)
                #pragma unroll
                for (int r = 0; r < 4; ++r) {
                    int m = m0 + wm + mi * 16 + q8 * 4 + r;
                    float v = acc[mi][ni][r];
                    if (EPI == 1) v += bs;
                    if (EPI == 3) { v = __expf(v - 20.f); colsum[ni] += v; }
                    C[(size_t)m * ldc + n] = f2bf(v);
                }
        }
        if (EPI == 3) {
            #pragma unroll
            for (int ni = 0; ni < 4; ++ni) {
                float s = colsum[ni];
                s += __shfl_xor(s, 16);
                s += __shfl_xor(s, 32);
                if (q8 == 0)
                    atomicAdd(&lbuf[zb * 1024 + n0 + wn + ni * 16 + r16], s);
            }
        }
    }
}

// ---------------------------------------------------------------------------
// prep: transpose+cast weights to bf16 [N,K]; concat theta/phi bias; zero lbuf
// ---------------------------------------------------------------------------
__global__ __launch_bounds__(256) void prep_w_kernel(
    const float* __restrict__ theta_w, const float* __restrict__ phi_w,
    const float* __restrict__ g_w, const float* __restrict__ o3_w,
    const float* __restrict__ theta_b, const float* __restrict__ phi_b,
    unsigned short* __restrict__ tpwT, unsigned short* __restrict__ gwT,
    unsigned short* __restrict__ o3wT, float* __restrict__ biasTP,
    float* __restrict__ lbuf)
{
    int t = blockIdx.x * 256 + threadIdx.x;
    if (t < 65536) {                       // tpwT [128][512]
        int n = t >> 9, k = t & 511;
        float v = (n < 64) ? theta_w[k * 64 + n] : phi_w[k * 64 + (n - 64)];
        tpwT[t] = f2bf(v);
    } else if (t < 196608) {               // gwT [256][512]
        int e = t - 65536; int n = e >> 9, k = e & 511;
        gwT[e] = f2bf(g_w[k * 256 + n]);
    } else if (t < 327680) {               // o3wT [512][256]
        int e = t - 196608; int n = e >> 8, k = e & 255;
        o3wT[e] = f2bf(o3_w[k * 512 + n]);
    } else if (t < 327808) {
        int j = t - 327680;
        biasTP[j] = (j < 64) ? theta_b[j] : phi_b[j - 64];
    } else if (t < 336000) {
        lbuf[t - 327808] = 0.f;
    }
}

__global__ __launch_bounds__(256) void cast_x_kernel(
    const float* __restrict__ x, unsigned short* __restrict__ xb)
{
    size_t t = (size_t)blockIdx.x * 256 + threadIdx.x;
    float4 v = ((const float4*)x)[t];
    ushort4 h;
    h.x = f2bf(v.x); h.y = f2bf(v.y); h.z = f2bf(v.z); h.w = f2bf(v.w);
    ((ushort4*)xb)[t] = h;
}

// phi maxpool: tpF[:,64:128] -> phiP [8][1024][64] bf16
__global__ __launch_bounds__(256) void maxpool_phi_kernel(
    const unsigned short* __restrict__ tpF, unsigned short* __restrict__ phiP)
{
    int t = blockIdx.x * 256 + threadIdx.x;   // 524288
    int f = t & 63, i = (t >> 6) & 1023, b = t >> 16;
    int ph = i >> 5, pw = i & 31;
    size_t base = ((size_t)(b * 64 + 2 * ph) * 64 + 2 * pw) * 128 + 64 + f;
    float v0 = bf2f(tpF[base]),        v1 = bf2f(tpF[base + 128]);
    float v2 = bf2f(tpF[base + 8192]), v3 = bf2f(tpF[base + 8192 + 128]);
    phiP[t] = f2bf(fmaxf(fmaxf(v0, v1), fmaxf(v2, v3)));
}

// g maxpool + transpose: gF [32768][256] -> gPT [8][256][1024] bf16
__global__ __launch_bounds__(256) void maxpoolT_g_kernel(
    const unsigned short* __restrict__ gF, unsigned short* __restrict__ gPT)
{
    __shared__ unsigned short tile[16][256];
    int b = blockIdx.y, i0 = blockIdx.x * 16, c = threadIdx.x;
    #pragma unroll
    for (int il = 0; il < 16; ++il) {
        int i = i0 + il, ph = i >> 5, pw = i & 31;
        size_t base = ((size_t)(b * 64 + 2 * ph) * 64 + 2 * pw) * 256 + c;
        float v0 = bf2f(gF[base]),         v1 = bf2f(gF[base + 256]);
        float v2 = bf2f(gF[base + 16384]), v3 = bf2f(gF[base + 16384 + 256]);
        tile[il][c] = f2bf(fmaxf(fmaxf(v0, v1), fmaxf(v2, v3)));
    }
    __syncthreads();
    unsigned short* dst = gPT + ((size_t)(b * 256 + c) * 1024 + i0);
    short8 v0, v1;
    #pragma unroll
    for (int il = 0; il < 8; ++il) { v0[il] = (short)tile[il][c]; v1[il] = (short)tile[il + 8][c]; }
    *(short8*)dst = v0;
    *(short8*)(dst + 8) = v1;
}

// gPT[b][c][i] *= 1/l[b][i]
__global__ __launch_bounds__(256) void scale_gpt_kernel(
    unsigned short* __restrict__ gPT, const float* __restrict__ lbuf)
{
    int t = blockIdx.x * 256 + threadIdx.x;   // 2097152
    int i = t & 1023, b = t >> 18;
    float rl = 1.0f / lbuf[b * 1024 + i];
    gPT[t] = f2bf(bf2f(gPT[t]) * rl);
}

// ---------------------------------------------------------------------------
extern "C" void kernel_launch(void* const* d_in, const int* in_sizes, int n_in,
                              void* d_out, int out_size, void* d_ws, size_t ws_size,
                              hipStream_t stream)
{
    const float* x       = (const float*)d_in[0];
    const float* theta_w = (const float*)d_in[1];
    const float* theta_b = (const float*)d_in[2];
    const float* phi_w   = (const float*)d_in[3];
    const float* phi_b   = (const float*)d_in[4];
    const float* g_w     = (const float*)d_in[5];
    const float* g_b     = (const float*)d_in[6];
    const float* o3_w    = (const float*)d_in[7];
    const float* o3_b    = (const float*)d_in[8];
    const float* gamma   = (const float*)d_in[9];

    char* ws = (char*)d_ws;
    const size_t MB = 1u << 20;
    unsigned short* tpwT = (unsigned short*)(ws);            // 128x512 bf16
    unsigned short* gwT  = (unsigned short*)(ws + 131072);   // 256x512
    unsigned short* o3wT = (unsigned short*)(ws + 393216);   // 512x256
    float* biasTP        = (float*)(ws + 655360);            // 128
    float* lbuf          = (float*)(ws + 655872);            // 8192
    unsigned short* gPT  = (unsigned short*)(ws + 1 * MB);   // [1,5)   MiB
    unsigned short* tpF  = (unsigned short*)(ws + 5 * MB);   // [5,13)
    unsigned short* phiP = (unsigned short*)(ws + 13 * MB);  // [13,14)
    unsigned short* gF   = (unsigned short*)(ws + 14 * MB);  // [14,30)
    unsigned short* xb   = (unsigned short*)(ws + 30 * MB);  // [30,62)  dead after tp-GEMM
    unsigned short* o_   = (unsigned short*)(ws + 30 * MB);  // [30,46)  alias xb (written later)
    unsigned short* sT   = (unsigned short*)d_out;           // 64 MiB scratch; final GEMM overwrites

    // 1. weight prep (+ lbuf zero)
    prep_w_kernel<<<1313, 256, 0, stream>>>(theta_w, phi_w, g_w, o3_w, theta_b, phi_b,
                                            tpwT, gwT, o3wT, biasTP, lbuf);
    // 2. cast x -> bf16
    cast_x_kernel<<<16384, 256, 0, stream>>>(x, xb);
    // 3. gF = xb . gwT^T + g_b        [32768,256]
    mfma_gemm<1><<<dim3(2, 256, 1), 256, 0, stream>>>(
        xb, gwT, gF, g_b, nullptr, nullptr, nullptr, 512, 512, 256, 512, 0, 0, 0);
    // 4. gPT = maxpool+transpose(gF)  [8][256][1024]
    maxpoolT_g_kernel<<<dim3(64, 8), 256, 0, stream>>>(gF, gPT);
    // 5. tpF = xb . tpwT^T + biasTP   [32768,128] (theta | phi)
    mfma_gemm<1><<<dim3(1, 256, 1), 256, 0, stream>>>(
        xb, tpwT, tpF, biasTP, nullptr, nullptr, nullptr, 512, 512, 128, 512, 0, 0, 0);
    // 6. phiP = maxpool(tpF[:,64:])   [8][1024][64]
    maxpool_phi_kernel<<<2048, 256, 0, stream>>>(tpF, phiP);
    // 7. sT = exp(theta . phiP^T - 20), lbuf[b][i] = column sums  [8][4096][1024]
    mfma_gemm<3><<<dim3(8, 32, 8), 256, 0, stream>>>(
        tpF, phiP, sT, nullptr, nullptr, nullptr, lbuf,
        128, 64, 1024, 64, 4096LL * 128, 1024LL * 64, 4096LL * 1024);
    // 8. gPT /= l
    scale_gpt_kernel<<<8192, 256, 0, stream>>>(gPT, lbuf);
    // 9. o = sT . gPT^T               [8][4096][256]
    mfma_gemm<0><<<dim3(2, 32, 8), 256, 0, stream>>>(
        sT, gPT, o_, nullptr, nullptr, nullptr, nullptr,
        1024, 1024, 256, 1024, 4096LL * 1024, 256LL * 1024, 4096LL * 256);
    // 10. out = gamma*(o . o3wT^T + o3_b) + x   [32768,512] fp32
    mfma_gemm<2><<<dim3(4, 256, 1), 256, 0, stream>>>(
        o_, o3wT, d_out, o3_b, gamma, x, nullptr, 256, 256, 512, 256, 0, 0, 0);
}

// Round 3
// 252.764 us; speedup vs baseline: 6.2469x; 1.0581x over previous
//
#include <hip/hip_runtime.h>
#include <cstdint>

typedef short short8 __attribute__((ext_vector_type(8)));
typedef float floatx4 __attribute__((ext_vector_type(4)));

__device__ __forceinline__ unsigned short f2bf(float f) {
    unsigned int u = __builtin_bit_cast(unsigned int, f);
    u += 0x7FFFu + ((u >> 16) & 1u);
    return (unsigned short)(u >> 16);
}
__device__ __forceinline__ float bf2f(unsigned short h) {
    unsigned int u = ((unsigned int)h) << 16;
    return __builtin_bit_cast(float, u);
}

__device__ __forceinline__ void async_copy16(const void* g, void* lds) {
    __builtin_amdgcn_global_load_lds(
        (const __attribute__((address_space(1))) void*)g,
        (__attribute__((address_space(3))) void*)lds, 16, 0, 0);
}

// ---------------------------------------------------------------------------
// m97-style bf16 MFMA GEMM. C[m,n] = sum_k A[m,k]*B[n,k]  (B given as [N,K])
// Block tile 128x128, BK=32, 4 waves (2x2), each wave 64x64 via 4x4 MFMA tiles.
// AFP32: A is fp32 in global; staged via register loads + convert (lda in floats).
// EPI: 1 = bf16 +bias[n]; 2 = fp32 gamma*(v+bias[n])+resid; 4 = no C write,
//      atomicAdd per-column sums of exp(v-20) into lbuf[zb*1024+n].
// ---------------------------------------------------------------------------
template<bool AFP32, int EPI>
__global__ __launch_bounds__(256) void mfma_gemm(
    const void* __restrict__ Avoid, const unsigned short* __restrict__ B,
    void* __restrict__ Cout, const float* __restrict__ bias,
    const float* __restrict__ gamma, const float* __restrict__ resid,
    float* __restrict__ lbuf,
    int lda, int ldb, int ldc, int K,
    long long sA, long long sB, long long sC)
{
    __shared__ unsigned short As[4096];   // [128][32] bf16
    __shared__ unsigned short Bs[4096];   // [128][32] bf16

    const int tid = threadIdx.x;
    const int wv = tid >> 6, ln = tid & 63;
    const int r16 = ln & 15, q8 = ln >> 4;
    const int wm = (wv >> 1) * 64, wn = (wv & 1) * 64;
    const int m0 = blockIdx.y * 128, n0 = blockIdx.x * 128;
    const int zb = blockIdx.z;

    const unsigned short* Bg = B + (long long)zb * sB;

    floatx4 acc[4][4] = {};

    for (int k0 = 0; k0 < K; k0 += 32) {
        if (AFP32) {
            const float* Af = (const float*)Avoid;
            #pragma unroll
            for (int p = 0; p < 4; ++p) {
                int u = p * 256 + tid;          // 1024 units of 4 floats
                int row = u >> 3, c4 = u & 7;
                float4 v = *(const float4*)(Af + (size_t)(m0 + row) * lda + k0 + c4 * 4);
                ushort4 h;
                h.x = f2bf(v.x); h.y = f2bf(v.y); h.z = f2bf(v.z); h.w = f2bf(v.w);
                *(ushort4*)&As[row * 32 + c4 * 4] = h;
            }
            #pragma unroll
            for (int q = 0; q < 2; ++q) {
                int chunk = wv * 2 + q;
                int e = (chunk << 9) + ln * 8;
                int row = e >> 5, col = e & 31;
                async_copy16(Bg + (size_t)(n0 + row) * ldb + (k0 + col), &Bs[chunk << 9]);
            }
        } else {
            const unsigned short* Ag = (const unsigned short*)Avoid + (long long)zb * sA;
            #pragma unroll
            for (int q = 0; q < 2; ++q) {
                int chunk = wv * 2 + q;
                int e = (chunk << 9) + ln * 8;
                int row = e >> 5, col = e & 31;
                async_copy16(Ag + (size_t)(m0 + row) * lda + (k0 + col), &As[chunk << 9]);
                async_copy16(Bg + (size_t)(n0 + row) * ldb + (k0 + col), &Bs[chunk << 9]);
            }
        }
        __syncthreads();

        short8 af[4], bff[4];
        #pragma unroll
        for (int i = 0; i < 4; ++i) {
            af[i]  = *(const short8*)&As[(wm + i * 16 + r16) * 32 + q8 * 8];
            bff[i] = *(const short8*)&Bs[(wn + i * 16 + r16) * 32 + q8 * 8];
        }
        #pragma unroll
        for (int mi = 0; mi < 4; ++mi)
            #pragma unroll
            for (int ni = 0; ni < 4; ++ni)
                acc[mi][ni] = __builtin_amdgcn_mfma_f32_16x16x32_bf16(
                    af[mi], bff[ni], acc[mi][ni], 0, 0, 0);
        __syncthreads();
    }

    if (EPI == 2) {
        float* C = (float*)Cout;
        const float gm = gamma[0];
        #pragma unroll
        for (int ni = 0; ni < 4; ++ni) {
            const int n = n0 + wn + ni * 16 + r16;
            const float bs = bias[n];
            #pragma unroll
            for (int mi = 0; mi < 4; ++mi)
                #pragma unroll
                for (int r = 0; r < 4; ++r) {
                    int m = m0 + wm + mi * 16 + q8 * 4 + r;
                    C[(size_t)m * ldc + n] = gm * (acc[mi][ni][r] + bs) + resid[(size_t)m * ldc + n];
                }
        }
    } else if (EPI == 4) {
        float colsum[4] = {0.f, 0.f, 0.f, 0.f};
        #pragma unroll
        for (int ni = 0; ni < 4; ++ni)
            #pragma unroll
            for (int mi = 0; mi < 4; ++mi)
                #pragma unroll
                for (int r = 0; r < 4; ++r)
                    colsum[ni] += __expf(acc[mi][ni][r] - 20.f);
        #pragma unroll
        for (int ni = 0; ni < 4; ++ni) {
            float s = colsum[ni];
            s += __shfl_xor(s, 16);
            s += __shfl_xor(s, 32);
            if (q8 == 0)
                atomicAdd(&lbuf[zb * 1024 + n0 + wn + ni * 16 + r16], s);
        }
    } else { // EPI == 1
        unsigned short* C = (unsigned short*)Cout + (long long)zb * sC;
        #pragma unroll
        for (int ni = 0; ni < 4; ++ni) {
            const int n = n0 + wn + ni * 16 + r16;
            const float bs = bias[n];
            #pragma unroll
            for (int mi = 0; mi < 4; ++mi)
                #pragma unroll
                for (int r = 0; r < 4; ++r) {
                    int m = m0 + wm + mi * 16 + q8 * 4 + r;
                    C[(size_t)m * ldc + n] = f2bf(acc[mi][ni][r] + bs);
                }
        }
    }
}

// ---------------------------------------------------------------------------
// Fused attention phase 2: o[b,j,c] = sum_i (exp(theta[j].phi[i]-20)/l[i]) * g[i,c]
// Block: j-tile 128, c-tile 128, loop i in chunks of 64. Grid (2, 32, 8).
// ---------------------------------------------------------------------------
__global__ __launch_bounds__(256) void attn_fused_kernel(
    const unsigned short* __restrict__ tpgF,  // [32768][384], theta = cols 0..63
    const unsigned short* __restrict__ phiP,  // [8][1024][64]
    const unsigned short* __restrict__ gPT,   // [8][256][1024]
    const float* __restrict__ lbuf,           // [8][1024]
    unsigned short* __restrict__ o_)          // [8][4096][256]
{
    __shared__ unsigned short th_s[128 * 72];
    __shared__ unsigned short ph_s[64 * 72];
    __shared__ unsigned short es[128 * 72];
    __shared__ unsigned short gs[128 * 72];
    __shared__ float rl_s[1024];

    const int tid = threadIdx.x, wv = tid >> 6, ln = tid & 63;
    const int r16 = ln & 15, q8 = ln >> 4;
    const int c0 = blockIdx.x * 128, j0 = blockIdx.y * 128, b = blockIdx.z;
    const int wm = (wv >> 1) * 64, wn = (wv & 1) * 64;

    // stage theta tile [128][64] (once) + reciprocal l
    {
        const unsigned short* src = tpgF + (size_t)(b * 4096 + j0) * 384;
        #pragma unroll
        for (int p = 0; p < 4; ++p) {
            int u = p * 256 + tid;
            int row = u >> 3, cu = u & 7;
            *(short8*)&th_s[row * 72 + cu * 8] =
                *(const short8*)(src + (size_t)row * 384 + cu * 8);
        }
        #pragma unroll
        for (int p = 0; p < 4; ++p) {
            int i = p * 256 + tid;
            rl_s[i] = 1.0f / lbuf[b * 1024 + i];
        }
    }

    floatx4 acc[4][4] = {};   // o accumulator (j x c), wave tile 64x64

    for (int i0 = 0; i0 < 1024; i0 += 64) {
        // stage phi chunk [64][64] and g chunk [128 c][64 i]
        #pragma unroll
        for (int p = 0; p < 2; ++p) {
            int u = p * 256 + tid;
            int row = u >> 3, cu = u & 7;
            *(short8*)&ph_s[row * 72 + cu * 8] =
                *(const short8*)(phiP + ((size_t)b * 1024 + i0 + row) * 64 + cu * 8);
        }
        #pragma unroll
        for (int p = 0; p < 4; ++p) {
            int u = p * 256 + tid;
            int row = u >> 3, cu = u & 7;
            *(short8*)&gs[row * 72 + cu * 8] =
                *(const short8*)(gPT + ((size_t)(b * 256 + c0 + row)) * 1024 + i0 + cu * 8);
        }
        __syncthreads();

        // e = theta . phi^T : wave wv computes j rows [wv*32, wv*32+32), i [0,64)
        floatx4 sacc[2][4] = {};
        #pragma unroll
        for (int ks = 0; ks < 2; ++ks) {
            short8 saf[2], sbf[4];
            #pragma unroll
            for (int mi = 0; mi < 2; ++mi)
                saf[mi] = *(const short8*)&th_s[(wv * 32 + mi * 16 + r16) * 72 + ks * 32 + q8 * 8];
            #pragma unroll
            for (int ni = 0; ni < 4; ++ni)
                sbf[ni] = *(const short8*)&ph_s[(ni * 16 + r16) * 72 + ks * 32 + q8 * 8];
            #pragma unroll
            for (int mi = 0; mi < 2; ++mi)
                #pragma unroll
                for (int ni = 0; ni < 4; ++ni)
                    sacc[mi][ni] = __builtin_amdgcn_mfma_f32_16x16x32_bf16(
                        saf[mi], sbf[ni], sacc[mi][ni], 0, 0, 0);
        }
        // exp, scale by 1/l[i], write e tile to LDS
        #pragma unroll
        for (int ni = 0; ni < 4; ++ni) {
            float rl = rl_s[i0 + ni * 16 + r16];
            #pragma unroll
            for (int mi = 0; mi < 2; ++mi)
                #pragma unroll
                for (int r = 0; r < 4; ++r) {
                    int jl = wv * 32 + mi * 16 + q8 * 4 + r;
                    int il = ni * 16 + r16;
                    es[jl * 72 + il] = f2bf(__expf(sacc[mi][ni][r] - 20.f) * rl);
                }
        }
        __syncthreads();

        // o += e . g^T  (K = 64 over il)
        #pragma unroll
        for (int ks = 0; ks < 2; ++ks) {
            short8 oaf[4], obf[4];
            #pragma unroll
            for (int mi = 0; mi < 4; ++mi)
                oaf[mi] = *(const short8*)&es[(wm + mi * 16 + r16) * 72 + ks * 32 + q8 * 8];
            #pragma unroll
            for (int ni = 0; ni < 4; ++ni)
                obf[ni] = *(const short8*)&gs[(wn + ni * 16 + r16) * 72 + ks * 32 + q8 * 8];
            #pragma unroll
            for (int mi = 0; mi < 4; ++mi)
                #pragma unroll
                for (int ni = 0; ni < 4; ++ni)
                    acc[mi][ni] = __builtin_amdgcn_mfma_f32_16x16x32_bf16(
                        oaf[mi], obf[ni], acc[mi][ni], 0, 0, 0);
        }
        __syncthreads();
    }

    #pragma unroll
    for (int ni = 0; ni < 4; ++ni)
        #pragma unroll
        for (int mi = 0; mi < 4; ++mi)
            #pragma unroll
            for (int r = 0; r < 4; ++r) {
                int j = j0 + wm + mi * 16 + q8 * 4 + r;
                int c = c0 + wn + ni * 16 + r16;
                o_[((size_t)b * 4096 + j) * 256 + c] = f2bf(acc[mi][ni][r]);
            }
}

// ---------------------------------------------------------------------------
// prep: fused weight transpose+cast [384][512] (theta|phi|g), o3wT [512][256],
// fused bias [384], zero lbuf.
// ---------------------------------------------------------------------------
__global__ __launch_bounds__(256) void prep_w_kernel(
    const float* __restrict__ theta_w, const float* __restrict__ phi_w,
    const float* __restrict__ g_w, const float* __restrict__ o3_w,
    const float* __restrict__ theta_b, const float* __restrict__ phi_b,
    const float* __restrict__ g_b,
    unsigned short* __restrict__ tpgwT, unsigned short* __restrict__ o3wT,
    float* __restrict__ biasTPG, float* __restrict__ lbuf)
{
    int t = blockIdx.x * 256 + threadIdx.x;
    if (t < 196608) {                      // tpgwT [384][512]
        int n = t >> 9, k = t & 511;
        float v = (n < 64) ? theta_w[k * 64 + n]
                : (n < 128) ? phi_w[k * 64 + (n - 64)]
                : g_w[k * 256 + (n - 128)];
        tpgwT[t] = f2bf(v);
    } else if (t < 327680) {               // o3wT [512][256]
        int e = t - 196608; int n = e >> 8, k = e & 255;
        o3wT[e] = f2bf(o3_w[k * 512 + n]);
    } else if (t < 328064) {               // biasTPG [384]
        int j = t - 327680;
        biasTPG[j] = (j < 64) ? theta_b[j] : (j < 128) ? phi_b[j - 64] : g_b[j - 128];
    } else if (t < 336256) {
        lbuf[t - 328064] = 0.f;
    }
}

// phi maxpool: tpgF cols [64,128) -> phiP [8][1024][64] bf16
__global__ __launch_bounds__(256) void maxpool_phi_kernel(
    const unsigned short* __restrict__ tpgF, unsigned short* __restrict__ phiP)
{
    int t = blockIdx.x * 256 + threadIdx.x;   // 524288
    int f = t & 63, i = (t >> 6) & 1023, b = t >> 16;
    int ph = i >> 5, pw = i & 31;
    size_t base = ((size_t)(b * 64 + 2 * ph) * 64 + 2 * pw) * 384 + 64 + f;
    float v0 = bf2f(tpgF[base]),         v1 = bf2f(tpgF[base + 384]);
    float v2 = bf2f(tpgF[base + 24576]), v3 = bf2f(tpgF[base + 24576 + 384]);
    phiP[t] = f2bf(fmaxf(fmaxf(v0, v1), fmaxf(v2, v3)));
}

// g maxpool + transpose: tpgF cols [128,384) -> gPT [8][256][1024] bf16
__global__ __launch_bounds__(256) void maxpoolT_g_kernel(
    const unsigned short* __restrict__ tpgF, unsigned short* __restrict__ gPT)
{
    __shared__ unsigned short tile[16][256];
    int b = blockIdx.y, i0 = blockIdx.x * 16, c = threadIdx.x;
    #pragma unroll
    for (int il = 0; il < 16; ++il) {
        int i = i0 + il, ph = i >> 5, pw = i & 31;
        size_t base = ((size_t)(b * 64 + 2 * ph) * 64 + 2 * pw) * 384 + 128 + c;
        float v0 = bf2f(tpgF[base]),         v1 = bf2f(tpgF[base + 384]);
        float v2 = bf2f(tpgF[base + 24576]), v3 = bf2f(tpgF[base + 24576 + 384]);
        tile[il][c] = f2bf(fmaxf(fmaxf(v0, v1), fmaxf(v2, v3)));
    }
    __syncthreads();
    unsigned short* dst = gPT + ((size_t)(b * 256 + c) * 1024 + i0);
    short8 v0, v1;
    #pragma unroll
    for (int il = 0; il < 8; ++il) { v0[il] = (short)tile[il][c]; v1[il] = (short)tile[il + 8][c]; }
    *(short8*)dst = v0;
    *(short8*)(dst + 8) = v1;
}

// ---------------------------------------------------------------------------
extern "C" void kernel_launch(void* const* d_in, const int* in_sizes, int n_in,
                              void* d_out, int out_size, void* d_ws, size_t ws_size,
                              hipStream_t stream)
{
    const float* x       = (const float*)d_in[0];
    const float* theta_w = (const float*)d_in[1];
    const float* theta_b = (const float*)d_in[2];
    const float* phi_w   = (const float*)d_in[3];
    const float* phi_b   = (const float*)d_in[4];
    const float* g_w     = (const float*)d_in[5];
    const float* g_b     = (const float*)d_in[6];
    const float* o3_w    = (const float*)d_in[7];
    const float* o3_b    = (const float*)d_in[8];
    const float* gamma   = (const float*)d_in[9];

    char* ws = (char*)d_ws;
    unsigned short* tpgwT  = (unsigned short*)(ws);             // 384x512 bf16
    unsigned short* o3wT   = (unsigned short*)(ws + 393216);    // 512x256
    float* biasTPG         = (float*)(ws + 655360);             // 384
    float* lbuf            = (float*)(ws + 656896);             // 8192
    unsigned short* tpgF   = (unsigned short*)(ws + (1u << 20));            // 24 MiB
    unsigned short* phiP   = (unsigned short*)(ws + (1u << 20) + 25165824); // 1 MiB
    unsigned short* gPT    = (unsigned short*)(ws + (1u << 20) + 26214400); // 4 MiB
    unsigned short* o_     = (unsigned short*)(ws + (1u << 20) + 30408704); // 16 MiB

    // 1. weight prep + lbuf zero
    prep_w_kernel<<<1314, 256, 0, stream>>>(theta_w, phi_w, g_w, o3_w,
                                            theta_b, phi_b, g_b,
                                            tpgwT, o3wT, biasTPG, lbuf);
    // 2. fused projections: tpgF = x . tpgwT^T + bias  [32768][384], reads fp32 x
    mfma_gemm<true, 1><<<dim3(3, 256, 1), 256, 0, stream>>>(
        x, tpgwT, tpgF, biasTPG, nullptr, nullptr, nullptr,
        512, 512, 384, 512, 0, 0, 0);
    // 3. pools
    maxpool_phi_kernel<<<2048, 256, 0, stream>>>(tpgF, phiP);
    maxpoolT_g_kernel<<<dim3(64, 8), 256, 0, stream>>>(tpgF, gPT);
    // 4. phase 1: l[b][i] = sum_j exp(theta[j].phi[i] - 20)
    mfma_gemm<false, 4><<<dim3(8, 32, 8), 256, 0, stream>>>(
        tpgF, phiP, nullptr, nullptr, nullptr, nullptr, lbuf,
        384, 64, 0, 64, 4096LL * 384, 1024LL * 64, 0);
    // 5. phase 2: fused e-recompute + o = (e/l) . g   [8][4096][256]
    attn_fused_kernel<<<dim3(2, 32, 8), 256, 0, stream>>>(tpgF, phiP, gPT, lbuf, o_);
    // 6. out = gamma*(o . o3wT^T + o3_b) + x   [32768][512] fp32
    mfma_gemm<false, 2><<<dim3(4, 256, 1), 256, 0, stream>>>(
        o_, o3wT, d_out, o3_b, gamma, x, nullptr,
        256, 256, 512, 256, 0, 0, 0);
}

// Round 4
// 238.561 us; speedup vs baseline: 6.6188x; 1.0595x over previous
//
#include <hip/hip_runtime.h>
#include <cstdint>

typedef short short8 __attribute__((ext_vector_type(8)));
typedef float floatx4 __attribute__((ext_vector_type(4)));

__device__ __forceinline__ unsigned short f2bf(float f) {
    unsigned int u = __builtin_bit_cast(unsigned int, f);
    u += 0x7FFFu + ((u >> 16) & 1u);
    return (unsigned short)(u >> 16);
}
__device__ __forceinline__ float bf2f(unsigned short h) {
    unsigned int u = ((unsigned int)h) << 16;
    return __builtin_bit_cast(float, u);
}

__device__ __forceinline__ void async_copy16(const void* g, void* lds) {
    __builtin_amdgcn_global_load_lds(
        (const __attribute__((address_space(1))) void*)g,
        (__attribute__((address_space(3))) void*)lds, 16, 0, 0);
}

// XOR swizzle (16-short granularity): slot koff = koff ^ (((row>>2)&3)<<4)
__device__ __forceinline__ int swz(int row, int koff) {
    return koff ^ (((row >> 2) & 3) << 4);
}

// ---------------------------------------------------------------------------
// m97-style bf16 MFMA GEMM (used for proj + final). C[m,n] = sum_k A[m,k]*B[n,k]
// AFP32: A fp32, staged via registers. EPI: 1 = bf16 +bias[n];
// 2 = fp32 gamma*(v+bias[n])+resid.
// ---------------------------------------------------------------------------
template<bool AFP32, int EPI>
__global__ __launch_bounds__(256) void mfma_gemm(
    const void* __restrict__ Avoid, const unsigned short* __restrict__ B,
    void* __restrict__ Cout, const float* __restrict__ bias,
    const float* __restrict__ gamma, const float* __restrict__ resid,
    int lda, int ldb, int ldc, int K)
{
    __shared__ unsigned short As[4096];   // [128][32] bf16
    __shared__ unsigned short Bs[4096];   // [128][32] bf16

    const int tid = threadIdx.x;
    const int wv = tid >> 6, ln = tid & 63;
    const int r16 = ln & 15, q8 = ln >> 4;
    const int wm = (wv >> 1) * 64, wn = (wv & 1) * 64;
    const int m0 = blockIdx.y * 128, n0 = blockIdx.x * 128;

    floatx4 acc[4][4] = {};

    for (int k0 = 0; k0 < K; k0 += 32) {
        if (AFP32) {
            const float* Af = (const float*)Avoid;
            #pragma unroll
            for (int p = 0; p < 4; ++p) {
                int u = p * 256 + tid;
                int row = u >> 3, c4 = u & 7;
                float4 v = *(const float4*)(Af + (size_t)(m0 + row) * lda + k0 + c4 * 4);
                ushort4 h;
                h.x = f2bf(v.x); h.y = f2bf(v.y); h.z = f2bf(v.z); h.w = f2bf(v.w);
                *(ushort4*)&As[row * 32 + c4 * 4] = h;
            }
            #pragma unroll
            for (int q = 0; q < 2; ++q) {
                int chunk = wv * 2 + q;
                int e = (chunk << 9) + ln * 8;
                int row = e >> 5, col = e & 31;
                async_copy16(B + (size_t)(n0 + row) * ldb + (k0 + col), &Bs[chunk << 9]);
            }
        } else {
            const unsigned short* Ag = (const unsigned short*)Avoid;
            #pragma unroll
            for (int q = 0; q < 2; ++q) {
                int chunk = wv * 2 + q;
                int e = (chunk << 9) + ln * 8;
                int row = e >> 5, col = e & 31;
                async_copy16(Ag + (size_t)(m0 + row) * lda + (k0 + col), &As[chunk << 9]);
                async_copy16(B + (size_t)(n0 + row) * ldb + (k0 + col), &Bs[chunk << 9]);
            }
        }
        __syncthreads();

        short8 af[4], bff[4];
        #pragma unroll
        for (int i = 0; i < 4; ++i) {
            af[i]  = *(const short8*)&As[(wm + i * 16 + r16) * 32 + q8 * 8];
            bff[i] = *(const short8*)&Bs[(wn + i * 16 + r16) * 32 + q8 * 8];
        }
        #pragma unroll
        for (int mi = 0; mi < 4; ++mi)
            #pragma unroll
            for (int ni = 0; ni < 4; ++ni)
                acc[mi][ni] = __builtin_amdgcn_mfma_f32_16x16x32_bf16(
                    af[mi], bff[ni], acc[mi][ni], 0, 0, 0);
        __syncthreads();
    }

    if (EPI == 2) {
        float* C = (float*)Cout;
        const float gm = gamma[0];
        #pragma unroll
        for (int ni = 0; ni < 4; ++ni) {
            const int n = n0 + wn + ni * 16 + r16;
            const float bs = bias[n];
            #pragma unroll
            for (int mi = 0; mi < 4; ++mi)
                #pragma unroll
                for (int r = 0; r < 4; ++r) {
                    int m = m0 + wm + mi * 16 + q8 * 4 + r;
                    C[(size_t)m * ldc + n] = gm * (acc[mi][ni][r] + bs) + resid[(size_t)m * ldc + n];
                }
        }
    } else {
        unsigned short* C = (unsigned short*)Cout;
        #pragma unroll
        for (int ni = 0; ni < 4; ++ni) {
            const int n = n0 + wn + ni * 16 + r16;
            const float bs = bias[n];
            #pragma unroll
            for (int mi = 0; mi < 4; ++mi)
                #pragma unroll
                for (int r = 0; r < 4; ++r) {
                    int m = m0 + wm + mi * 16 + q8 * 4 + r;
                    C[(size_t)m * ldc + n] = f2bf(acc[mi][ni][r] + bs);
                }
        }
    }
}

// ---------------------------------------------------------------------------
// Phase 1: l[b][i] = sum_j exp(theta[b,j].phi[b,i] - 20)
// Grid (4 j-splits, 16 i-tiles of 64, 8 b) = 512 blocks.
// ---------------------------------------------------------------------------
__global__ __launch_bounds__(256) void phase1_l_kernel(
    const unsigned short* __restrict__ tpgF,   // [32768][384], theta cols 0..63
    const unsigned short* __restrict__ phiP,   // [8][1024][64]
    float* __restrict__ lbuf)                  // [8][1024] (pre-zeroed)
{
    __shared__ unsigned short th_s[8192];   // [128][64]
    __shared__ unsigned short ph_s[4096];   // [64][64]
    const int tid = threadIdx.x, wv = tid >> 6, ln = tid & 63;
    const int r16 = ln & 15, q8 = ln >> 4, lsub = ln >> 3, l8 = ln & 7;
    const int jsp = blockIdx.x, i0 = blockIdx.y * 64, b = blockIdx.z;

    #pragma unroll
    for (int q = 0; q < 2; ++q) {
        int chunk = wv * 2 + q, row = chunk * 8 + lsub;
        int so = swz(row, l8 * 8);
        async_copy16(phiP + (size_t)(b * 1024 + i0 + row) * 64 + so, &ph_s[chunk * 512]);
    }

    float colsum[4] = {0.f, 0.f, 0.f, 0.f};
    for (int jc = 0; jc < 8; ++jc) {
        const int j0 = jsp * 1024 + jc * 128;
        __syncthreads();
        #pragma unroll
        for (int q = 0; q < 4; ++q) {
            int chunk = wv * 4 + q, row = chunk * 8 + lsub;
            int so = swz(row, l8 * 8);
            async_copy16(tpgF + (size_t)(b * 4096 + j0 + row) * 384 + so, &th_s[chunk * 512]);
        }
        __syncthreads();

        floatx4 sacc[2][4] = {};
        #pragma unroll
        for (int ks = 0; ks < 2; ++ks) {
            short8 af[2], bf[4];
            #pragma unroll
            for (int mi = 0; mi < 2; ++mi)
                af[mi] = *(const short8*)&th_s[(wv * 32 + mi * 16 + r16) * 64 + swz(r16, ks * 32 + q8 * 8)];
            #pragma unroll
            for (int ni = 0; ni < 4; ++ni)
                bf[ni] = *(const short8*)&ph_s[(ni * 16 + r16) * 64 + swz(r16, ks * 32 + q8 * 8)];
            #pragma unroll
            for (int mi = 0; mi < 2; ++mi)
                #pragma unroll
                for (int ni = 0; ni < 4; ++ni)
                    sacc[mi][ni] = __builtin_amdgcn_mfma_f32_16x16x32_bf16(
                        af[mi], bf[ni], sacc[mi][ni], 0, 0, 0);
        }
        #pragma unroll
        for (int mi = 0; mi < 2; ++mi)
            #pragma unroll
            for (int ni = 0; ni < 4; ++ni)
                #pragma unroll
                for (int r = 0; r < 4; ++r)
                    colsum[ni] += __expf(sacc[mi][ni][r] - 20.f);
    }
    #pragma unroll
    for (int ni = 0; ni < 4; ++ni) {
        float s = colsum[ni];
        s += __shfl_xor(s, 16);
        s += __shfl_xor(s, 32);
        if (q8 == 0) atomicAdd(&lbuf[b * 1024 + i0 + ni * 16 + r16], s);
    }
}

// ---------------------------------------------------------------------------
// Fused attention phase 2: o[b,j,c] = sum_i exp(theta[j].phi[i]-20) * g'[c,i]
// (g' pre-scaled by 1/l). j-tile 64, c full 256, i chunks of 64. Grid (64, 8).
// ---------------------------------------------------------------------------
__global__ __launch_bounds__(256) void attn_fused_kernel(
    const unsigned short* __restrict__ tpgF,  // [32768][384], theta cols 0..63
    const unsigned short* __restrict__ phiP,  // [8][1024][64]
    const unsigned short* __restrict__ gPT,   // [8][256][1024], pre-scaled 1/l
    unsigned short* __restrict__ o_)          // [8][4096][256]
{
    __shared__ unsigned short th_es[4096];    // theta [64][64], then es (aliased)
    __shared__ unsigned short ph_s[4096];     // phi chunk [64][64]
    __shared__ unsigned short gs[16384];      // g chunk [256][64]

    const int tid = threadIdx.x, wv = tid >> 6, ln = tid & 63;
    const int r16 = ln & 15, q8 = ln >> 4, lsub = ln >> 3, l8 = ln & 7;
    const int j0 = blockIdx.x * 64, b = blockIdx.y;

    // stage theta tile [64][64] (swizzled), hoist to registers
    #pragma unroll
    for (int q = 0; q < 2; ++q) {
        int chunk = wv * 2 + q, row = chunk * 8 + lsub;
        int so = swz(row, l8 * 8);
        async_copy16(tpgF + (size_t)(b * 4096 + j0 + row) * 384 + so, &th_es[chunk * 512]);
    }
    __syncthreads();
    short8 thf[4][2];
    #pragma unroll
    for (int mi = 0; mi < 4; ++mi)
        #pragma unroll
        for (int ks = 0; ks < 2; ++ks)
            thf[mi][ks] = *(const short8*)&th_es[(mi * 16 + r16) * 64 + swz(r16, ks * 32 + q8 * 8)];

    floatx4 acc[4][4] = {};

    for (int i0 = 0; i0 < 1024; i0 += 64) {
        __syncthreads();   // prev o-MFMA done (and th reg-loads on first iter)
        #pragma unroll
        for (int q = 0; q < 2; ++q) {
            int chunk = wv * 2 + q, row = chunk * 8 + lsub;
            int so = swz(row, l8 * 8);
            async_copy16(phiP + (size_t)(b * 1024 + i0 + row) * 64 + so, &ph_s[chunk * 512]);
        }
        #pragma unroll
        for (int q = 0; q < 8; ++q) {
            int chunk = wv * 8 + q, c = chunk * 8 + lsub;
            int so = swz(c, l8 * 8);
            async_copy16(gPT + ((size_t)(b * 256 + c)) * 1024 + i0 + so, &gs[chunk * 512]);
        }
        __syncthreads();   // staging landed

        // s = theta . phi^T for i-cols [wv*16, wv*16+16)
        floatx4 sacc[4] = {};
        #pragma unroll
        for (int ks = 0; ks < 2; ++ks) {
            short8 pf = *(const short8*)&ph_s[(wv * 16 + r16) * 64 + swz(r16, ks * 32 + q8 * 8)];
            #pragma unroll
            for (int mi = 0; mi < 4; ++mi)
                sacc[mi] = __builtin_amdgcn_mfma_f32_16x16x32_bf16(
                    thf[mi][ks], pf, sacc[mi], 0, 0, 0);
        }
        // es[j][i] = exp(s - 20), swizzled store (conflict-free)
        #pragma unroll
        for (int mi = 0; mi < 4; ++mi)
            #pragma unroll
            for (int r = 0; r < 4; ++r) {
                int j = mi * 16 + q8 * 4 + r;           // (j>>2)&3 == q8
                th_es[j * 64 + (((wv ^ q8) << 4) | r16)] = f2bf(__expf(sacc[mi][r] - 20.f));
            }
        __syncthreads();   // es ready

        // o += es . gs^T  (c-cols wv*64..wv*64+64)
        #pragma unroll
        for (int ks = 0; ks < 2; ++ks) {
            short8 ef[4], gf[4];
            #pragma unroll
            for (int mi = 0; mi < 4; ++mi)
                ef[mi] = *(const short8*)&th_es[(mi * 16 + r16) * 64 + swz(r16, ks * 32 + q8 * 8)];
            #pragma unroll
            for (int ni = 0; ni < 4; ++ni)
                gf[ni] = *(const short8*)&gs[(wv * 64 + ni * 16 + r16) * 64 + swz(r16, ks * 32 + q8 * 8)];
            #pragma unroll
            for (int mi = 0; mi < 4; ++mi)
                #pragma unroll
                for (int ni = 0; ni < 4; ++ni)
                    acc[mi][ni] = __builtin_amdgcn_mfma_f32_16x16x32_bf16(
                        ef[mi], gf[ni], acc[mi][ni], 0, 0, 0);
        }
    }

    #pragma unroll
    for (int mi = 0; mi < 4; ++mi)
        #pragma unroll
        for (int ni = 0; ni < 4; ++ni)
            #pragma unroll
            for (int r = 0; r < 4; ++r) {
                int j = j0 + mi * 16 + q8 * 4 + r;
                int c = wv * 64 + ni * 16 + r16;
                o_[((size_t)b * 4096 + j) * 256 + c] = f2bf(acc[mi][ni][r]);
            }
}

// ---------------------------------------------------------------------------
// prep: weight transpose+cast [384][512] (theta|phi|g), o3wT [512][256],
// fused bias [384], zero lbuf.
// ---------------------------------------------------------------------------
__global__ __launch_bounds__(256) void prep_w_kernel(
    const float* __restrict__ theta_w, const float* __restrict__ phi_w,
    const float* __restrict__ g_w, const float* __restrict__ o3_w,
    const float* __restrict__ theta_b, const float* __restrict__ phi_b,
    const float* __restrict__ g_b,
    unsigned short* __restrict__ tpgwT, unsigned short* __restrict__ o3wT,
    float* __restrict__ biasTPG, float* __restrict__ lbuf)
{
    int t = blockIdx.x * 256 + threadIdx.x;
    if (t < 196608) {                      // tpgwT [384][512]
        int n = t >> 9, k = t & 511;
        float v = (n < 64) ? theta_w[k * 64 + n]
                : (n < 128) ? phi_w[k * 64 + (n - 64)]
                : g_w[k * 256 + (n - 128)];
        tpgwT[t] = f2bf(v);
    } else if (t < 327680) {               // o3wT [512][256]
        int e = t - 196608; int n = e >> 8, k = e & 255;
        o3wT[e] = f2bf(o3_w[k * 512 + n]);
    } else if (t < 328064) {               // biasTPG [384]
        int j = t - 327680;
        biasTPG[j] = (j < 64) ? theta_b[j] : (j < 128) ? phi_b[j - 64] : g_b[j - 128];
    } else if (t < 336256) {
        lbuf[t - 328064] = 0.f;
    }
}

// phi maxpool: tpgF cols [64,128) -> phiP [8][1024][64] bf16
__global__ __launch_bounds__(256) void maxpool_phi_kernel(
    const unsigned short* __restrict__ tpgF, unsigned short* __restrict__ phiP)
{
    int t = blockIdx.x * 256 + threadIdx.x;   // 524288
    int f = t & 63, i = (t >> 6) & 1023, b = t >> 16;
    int ph = i >> 5, pw = i & 31;
    size_t base = ((size_t)(b * 64 + 2 * ph) * 64 + 2 * pw) * 384 + 64 + f;
    float v0 = bf2f(tpgF[base]),         v1 = bf2f(tpgF[base + 384]);
    float v2 = bf2f(tpgF[base + 24576]), v3 = bf2f(tpgF[base + 24576 + 384]);
    phiP[t] = f2bf(fmaxf(fmaxf(v0, v1), fmaxf(v2, v3)));
}

// g maxpool + transpose + 1/l scale: tpgF cols [128,384) -> gPT [8][256][1024]
__global__ __launch_bounds__(256) void maxpoolT_g_kernel(
    const unsigned short* __restrict__ tpgF, const float* __restrict__ lbuf,
    unsigned short* __restrict__ gPT)
{
    __shared__ unsigned short tile[16][256];
    __shared__ float rls[16];
    int b = blockIdx.y, i0 = blockIdx.x * 16, c = threadIdx.x;
    if (c < 16) rls[c] = 1.0f / lbuf[b * 1024 + i0 + c];
    __syncthreads();
    #pragma unroll
    for (int il = 0; il < 16; ++il) {
        int i = i0 + il, ph = i >> 5, pw = i & 31;
        size_t base = ((size_t)(b * 64 + 2 * ph) * 64 + 2 * pw) * 384 + 128 + c;
        float v0 = bf2f(tpgF[base]),         v1 = bf2f(tpgF[base + 384]);
        float v2 = bf2f(tpgF[base + 24576]), v3 = bf2f(tpgF[base + 24576 + 384]);
        tile[il][c] = f2bf(fmaxf(fmaxf(v0, v1), fmaxf(v2, v3)) * rls[il]);
    }
    __syncthreads();
    unsigned short* dst = gPT + ((size_t)(b * 256 + c) * 1024 + i0);
    short8 v0, v1;
    #pragma unroll
    for (int il = 0; il < 8; ++il) { v0[il] = (short)tile[il][c]; v1[il] = (short)tile[il + 8][c]; }
    *(short8*)dst = v0;
    *(short8*)(dst + 8) = v1;
}

// ---------------------------------------------------------------------------
extern "C" void kernel_launch(void* const* d_in, const int* in_sizes, int n_in,
                              void* d_out, int out_size, void* d_ws, size_t ws_size,
                              hipStream_t stream)
{
    const float* x       = (const float*)d_in[0];
    const float* theta_w = (const float*)d_in[1];
    const float* theta_b = (const float*)d_in[2];
    const float* phi_w   = (const float*)d_in[3];
    const float* phi_b   = (const float*)d_in[4];
    const float* g_w     = (const float*)d_in[5];
    const float* g_b     = (const float*)d_in[6];
    const float* o3_w    = (const float*)d_in[7];
    const float* o3_b    = (const float*)d_in[8];
    const float* gamma   = (const float*)d_in[9];

    char* ws = (char*)d_ws;
    unsigned short* tpgwT  = (unsigned short*)(ws);             // 384x512 bf16
    unsigned short* o3wT   = (unsigned short*)(ws + 393216);    // 512x256
    float* biasTPG         = (float*)(ws + 655360);             // 384
    float* lbuf            = (float*)(ws + 656896);             // 8192
    unsigned short* tpgF   = (unsigned short*)(ws + (1u << 20));            // 24 MiB
    unsigned short* phiP   = (unsigned short*)(ws + (1u << 20) + 25165824); // 1 MiB
    unsigned short* gPT    = (unsigned short*)(ws + (1u << 20) + 26214400); // 4 MiB
    unsigned short* o_     = (unsigned short*)(ws + (1u << 20) + 30408704); // 16 MiB

    // 1. weight prep + lbuf zero
    prep_w_kernel<<<1314, 256, 0, stream>>>(theta_w, phi_w, g_w, o3_w,
                                            theta_b, phi_b, g_b,
                                            tpgwT, o3wT, biasTPG, lbuf);
    // 2. fused projections: tpgF = x . tpgwT^T + bias  [32768][384]
    mfma_gemm<true, 1><<<dim3(3, 256), 256, 0, stream>>>(
        x, tpgwT, tpgF, biasTPG, nullptr, nullptr, 512, 512, 384, 512);
    // 3. phi pool
    maxpool_phi_kernel<<<2048, 256, 0, stream>>>(tpgF, phiP);
    // 4. phase 1: l[b][i] = sum_j exp(theta[j].phi[i] - 20)
    phase1_l_kernel<<<dim3(4, 16, 8), 256, 0, stream>>>(tpgF, phiP, lbuf);
    // 5. g pool + transpose + 1/l scale
    maxpoolT_g_kernel<<<dim3(64, 8), 256, 0, stream>>>(tpgF, lbuf, gPT);
    // 6. phase 2: fused e-recompute + o = e . g'   [8][4096][256]
    attn_fused_kernel<<<dim3(64, 8), 256, 0, stream>>>(tpgF, phiP, gPT, o_);
    // 7. out = gamma*(o . o3wT^T + o3_b) + x   [32768][512] fp32
    mfma_gemm<false, 2><<<dim3(4, 256), 256, 0, stream>>>(
        o_, o3wT, d_out, o3_b, gamma, x, 256, 256, 512, 256);
}